// Round 2
// baseline (282.072 us; speedup 1.0000x reference)
//
#include <hip/hip_runtime.h>

#define TABLE_ROWS 1025
#define HIDDEN 128
#define SEQ 512
#define BATCH 2

// Kernel 1: A_ss[t,h] = sum_k pe_ss[t,k]*W[h,k] + b[h]
//           A_ee[t,h] = sum_k pe_ee[t,k]*W[h,HIDDEN+k]
// A layout in d_ws: [2][TABLE_ROWS][HIDDEN] fp32.
__global__ __launch_bounds__(128) void precompute_tables(
    const float* __restrict__ pe_ss, const float* __restrict__ pe_ee,
    const float* __restrict__ W, const float* __restrict__ bias,
    float* __restrict__ A)
{
    constexpr int ROWS = 8;
    constexpr int NBLK = (TABLE_ROWS + ROWS - 1) / ROWS;  // 129 blocks per table
    const int table = (blockIdx.x >= NBLK) ? 1 : 0;
    const int row0 = (blockIdx.x - table * NBLK) * ROWS;
    const float* __restrict__ pe = table ? pe_ee : pe_ss;
    const int h = threadIdx.x;

    __shared__ float s_rows[ROWS][HIDDEN];
    #pragma unroll
    for (int r = 0; r < ROWS; ++r) {
        int row = row0 + r;
        s_rows[r][h] = (row < TABLE_ROWS) ? pe[row * HIDDEN + h] : 0.0f;
    }
    __syncthreads();

    float acc[ROWS];
    const float bh = table ? 0.0f : bias[h];
    #pragma unroll
    for (int r = 0; r < ROWS; ++r) acc[r] = bh;

    // thread h reads W[h, table*128 + 0..127] as 32 float4s (L1/L2 resident)
    const float4* __restrict__ w4 =
        reinterpret_cast<const float4*>(W + (size_t)h * (2 * HIDDEN) + table * HIDDEN);
    #pragma unroll
    for (int k4 = 0; k4 < HIDDEN / 4; ++k4) {
        float4 w = w4[k4];
        #pragma unroll
        for (int r = 0; r < ROWS; ++r) {
            acc[r] = fmaf(s_rows[r][4 * k4 + 0], w.x, acc[r]);
            acc[r] = fmaf(s_rows[r][4 * k4 + 1], w.y, acc[r]);
            acc[r] = fmaf(s_rows[r][4 * k4 + 2], w.z, acc[r]);
            acc[r] = fmaf(s_rows[r][4 * k4 + 3], w.w, acc[r]);
        }
    }

    float* __restrict__ Aout = A + (size_t)table * TABLE_ROWS * HIDDEN;
    #pragma unroll
    for (int r = 0; r < ROWS; ++r) {
        int row = row0 + r;
        if (row < TABLE_ROWS) Aout[row * HIDDEN + h] = acc[r];
    }
}

// Kernel 2: out[b,i,j,h] = relu(A_ss[ds+512][h] + A_ee[de+512][h])
// 32 lanes per (b,i,j) row, float4 per lane. Write-BW bound.
__global__ __launch_bounds__(256) void gather_fuse(
    const int* __restrict__ pos_s, const int* __restrict__ pos_e,
    const float* __restrict__ A, float* __restrict__ out)
{
    const float* __restrict__ A_ss = A;
    const float* __restrict__ A_ee = A + (size_t)TABLE_ROWS * HIDDEN;
    const long total4 = (long)BATCH * SEQ * SEQ * (HIDDEN / 4);  // 16,777,216
    const long stride = (long)gridDim.x * blockDim.x;

    for (long t = (long)blockIdx.x * blockDim.x + threadIdx.x; t < total4; t += stride) {
        const int lane = (int)(t & (HIDDEN / 4 - 1));  // float4 slot within row
        const long row = t >> 5;                       // (b*SEQ + i)*SEQ + j
        const int j  = (int)(row & (SEQ - 1));
        const int bi = (int)(row >> 9);                // b*SEQ + i
        const int b  = bi >> 9;
        const int bj = (b << 9) + j;

        const int tss = pos_s[bi] - pos_s[bj] + 512;
        const int tee = pos_e[bi] - pos_e[bj] + 512;

        const float4 va = reinterpret_cast<const float4*>(A_ss + (size_t)tss * HIDDEN)[lane];
        const float4 vb = reinterpret_cast<const float4*>(A_ee + (size_t)tee * HIDDEN)[lane];

        float4 o;
        o.x = fmaxf(va.x + vb.x, 0.0f);
        o.y = fmaxf(va.y + vb.y, 0.0f);
        o.z = fmaxf(va.z + vb.z, 0.0f);
        o.w = fmaxf(va.w + vb.w, 0.0f);
        reinterpret_cast<float4*>(out)[t] = o;
    }
}

extern "C" void kernel_launch(void* const* d_in, const int* in_sizes, int n_in,
                              void* d_out, int out_size, void* d_ws, size_t ws_size,
                              hipStream_t stream) {
    const int*   pos_s = (const int*)d_in[0];
    const int*   pos_e = (const int*)d_in[1];
    const float* pe_ss = (const float*)d_in[2];
    // d_in[3] = pe_se, d_in[4] = pe_es: dead in the reference, skipped.
    const float* pe_ee = (const float*)d_in[5];
    const float* W     = (const float*)d_in[6];
    const float* bias  = (const float*)d_in[7];

    float* A = (float*)d_ws;  // [2][1025][128] fp32 = 1,049,600 B

    constexpr int NBLK = (TABLE_ROWS + 7) / 8;  // 129
    precompute_tables<<<2 * NBLK, 128, 0, stream>>>(pe_ss, pe_ee, W, bias, A);
    gather_fuse<<<2048, 256, 0, stream>>>(pos_s, pos_e, A, (float*)d_out);
}